// Round 5
// baseline (739.523 us; speedup 1.0000x reference)
//
#include <hip/hip_runtime.h>
#include <math.h>

#define NB 32
#define NM 8
#define HOBJ 1024
// exchange buffer: per-group region of 8 rows x 18 f2, region stride 152 f2
// (152 f2 = 304 f32 == 16 mod 32 -> adjacent groups staggered 16 banks)
#define EXROW 18
#define EXREG 152

// zero-instruction compiler memory fence: the wave-local LDS exchange relies on
// same-wave DS program order (hardware-guaranteed); this stops the COMPILER from
// reordering the float4-punned stores vs float2 loads (TBAA says they don't alias).
#define CFENCE() __asm__ volatile("" ::: "memory")

// ---------- complex helpers ----------
__device__ __forceinline__ float2 cmul(float2 a, float2 b) {
    return make_float2(fmaf(a.x, b.x, -a.y * b.y), fmaf(a.x, b.y, a.y * b.x));
}

__constant__ float COS16[10] = {1.f, 0.9238795325f, 0.7071067812f, 0.3826834324f, 0.f,
                                -0.3826834324f, -0.7071067812f, -0.9238795325f, -1.f, -0.9238795325f};
__constant__ float SIN16[10] = {0.f, 0.3826834324f, 0.7071067812f, 0.9238795325f, 1.f,
                                0.9238795325f, 0.7071067812f, 0.3826834324f, 0.f, -0.3826834324f};

template <int S>
__device__ __forceinline__ void dft4(float2 a, float2 b, float2 c, float2 d,
                                     float2* o0, float2* o1, float2* o2, float2* o3) {
    float2 apc = make_float2(a.x + c.x, a.y + c.y);
    float2 amc = make_float2(a.x - c.x, a.y - c.y);
    float2 bpd = make_float2(b.x + d.x, b.y + d.y);
    float2 bmd = make_float2(b.x - d.x, b.y - d.y);
    float2 ib = (S < 0) ? make_float2(bmd.y, -bmd.x) : make_float2(-bmd.y, bmd.x);
    *o0 = make_float2(apc.x + bpd.x, apc.y + bpd.y);
    *o1 = make_float2(amc.x + ib.x, amc.y + ib.y);
    *o2 = make_float2(apc.x - bpd.x, apc.y - bpd.y);
    *o3 = make_float2(amc.x - ib.x, amc.y - ib.y);
}

template <int S>
__device__ __forceinline__ void fft16(float2 v[16]) {
    float2 t[16];
#pragma unroll
    for (int b = 0; b < 4; ++b)
        dft4<S>(v[b], v[4 + b], v[8 + b], v[12 + b],
                &t[4 * b + 0], &t[4 * b + 1], &t[4 * b + 2], &t[4 * b + 3]);
#pragma unroll
    for (int b = 1; b < 4; ++b)
#pragma unroll
        for (int c = 1; c < 4; ++c) {
            int j = b * c;  // 1..9
            float2 w = make_float2(COS16[j], (S < 0) ? -SIN16[j] : SIN16[j]);
            t[4 * b + c] = cmul(t[4 * b + c], w);
        }
#pragma unroll
    for (int c = 0; c < 4; ++c)
        dft4<S>(t[c], t[4 + c], t[8 + c], t[12 + c],
                &v[c + 0], &v[c + 4], &v[c + 8], &v[c + 12]);
}

// 256-point FFT, 16 lanes of ONE wave cooperate (t in [0,16)); BARRIER-FREE.
// in v[n1] = x[16*n1 + t]; out v[k2] = X[16*k2 + t]. Unscaled.
// ex = per-group LDS region ([8][EXROW] f2, reused in two halves).
// Same-wave DS ops execute in program order; CFENCE() pins the compiler order.
template <int S>
__device__ __forceinline__ void fft256w(float2 v[16], int t, float2* ex) {
    fft16<S>(v);
#pragma unroll
    for (int k = 1; k < 16; ++k) {
        float sn, cs;
        __sincosf((float)S * 0.024543692606f * (float)(t * k), &sn, &cs);  // 2pi/256
        v[k] = cmul(v[k], make_float2(cs, sn));
    }
    CFENCE();  // don't sink these writes below the reads (also guards prior call's reads)
    // half A: lanes t<8 deposit their row M[t][0..15]
    if (t < 8) {
        float2* row = ex + t * EXROW;
#pragma unroll
        for (int c = 0; c < 8; ++c) {
            float4 f;
            f.x = v[2 * c].x; f.y = v[2 * c].y; f.z = v[2 * c + 1].x; f.w = v[2 * c + 1].y;
            *(float4*)(row + 2 * c) = f;
        }
    }
    CFENCE();
    float2 w0[8];
#pragma unroll
    for (int j = 0; j < 8; ++j) w0[j] = ex[j * EXROW + t];  // M[j][t], j<8
    CFENCE();
    // half B: lanes t>=8 deposit their row (reuses rows 0..7; wave-order safe)
    if (t >= 8) {
        float2* row = ex + (t - 8) * EXROW;
#pragma unroll
        for (int c = 0; c < 8; ++c) {
            float4 f;
            f.x = v[2 * c].x; f.y = v[2 * c].y; f.z = v[2 * c + 1].x; f.w = v[2 * c + 1].y;
            *(float4*)(row + 2 * c) = f;
        }
    }
    CFENCE();
#pragma unroll
    for (int j = 0; j < 8; ++j) v[8 + j] = ex[j * EXROW + t];  // M[8+j][t]
    CFENCE();
#pragma unroll
    for (int j = 0; j < 8; ++j) v[j] = w0[j];
    fft16<S>(v);
}

// load 16 row elements (coalesced), row r of image img
__device__ __forceinline__ void load_row(float2 v[16], const float2* img, int r, int t) {
    const float2* p = img + (size_t)r * 256 + t;
#pragma unroll
    for (int j = 0; j < 16; ++j) v[j] = p[16 * j];
}
// store v transposed: dst[(16*k+t)*256 + r]
__device__ __forceinline__ void store_t(const float2 v[16], float2* dst, int r, int t, float sc) {
    float2* p = dst + (size_t)t * 256 + r;
#pragma unroll
    for (int k = 0; k < 16; ++k) {
        float2 o = make_float2(v[k].x * sc, v[k].y * sc);
        p[(size_t)(16 * k) * 256] = o;
    }
}

// ---------- P1: build uprobe rows + xF ; write T -> [kx][y] ----------
__global__ void k_p1(const float* __restrict__ probe, const float* __restrict__ opr_w,
                     const int* __restrict__ indices, float2* __restrict__ dst, int b0) {
    __shared__ __align__(16) float2 lds[16 * EXREG];
    int tt = threadIdx.x;
    int t = tt & 15, g = tt >> 4;
    int rowg = blockIdx.x, m = blockIdx.y, bl = blockIdx.z;
    int y = rowg * 16 + g;
    int idx = indices[b0 + bl];
    float2* ex = lds + g * EXREG;
    float2 v[16];
    if (m == 0) {
        float w0 = opr_w[idx * 4 + 0], w1 = opr_w[idx * 4 + 1];
        float w2 = opr_w[idx * 4 + 2], w3 = opr_w[idx * 4 + 3];
        const float2* p = (const float2*)probe;
        size_t rb = (size_t)y * 256;
#pragma unroll
        for (int j = 0; j < 16; ++j) {
            size_t o = rb + 16 * j + t;
            float2 p0 = p[o];
            float2 p1 = p[(size_t)(1 * NM) * 65536 + o];
            float2 p2 = p[(size_t)(2 * NM) * 65536 + o];
            float2 p3 = p[(size_t)(3 * NM) * 65536 + o];
            v[j] = make_float2(w0 * p0.x + w1 * p1.x + w2 * p2.x + w3 * p3.x,
                               w0 * p0.y + w1 * p1.y + w2 * p2.y + w3 * p3.y);
        }
    } else {
        load_row(v, (const float2*)probe + (size_t)m * 65536, y, t);
    }
    fft256w<-1>(v, t, ex);
    store_t(v, dst + (size_t)(bl * NM + m) * 65536, y, t, 1.0f);
}

// ---------- P2: rows=kx: yF, 2D shift phase, yI ; write T -> [y][kx] ----------
__global__ void k_p2(const float* __restrict__ positions, const int* __restrict__ indices,
                     const float2* __restrict__ src, float2* __restrict__ dst, int b0) {
    __shared__ __align__(16) float2 lds[16 * EXREG];
    int tt = threadIdx.x;
    int t = tt & 15, g = tt >> 4;
    int rowg = blockIdx.x, m = blockIdx.y, bl = blockIdx.z;
    int r = rowg * 16 + g;  // = kx
    int idx = indices[b0 + bl];
    float py = positions[idx * 2 + 0], px = positions[idx * 2 + 1];
    float fr0 = py - rintf(py), fr1 = px - rintf(px);
    float fxv = (float)((r < 128) ? r : r - 256) * (1.0f / 256.0f);
    float2* ex = lds + g * EXREG;
    size_t ib = (size_t)(bl * NM + m) * 65536;
    float2 v[16];
    load_row(v, src + ib, r, t);
    fft256w<-1>(v, t, ex);
#pragma unroll
    for (int k = 0; k < 16; ++k) {
        int ky = 16 * k + t;
        float fyv = (float)((ky < 128) ? ky : ky - 256) * (1.0f / 256.0f);
        float ang = -6.2831853071795865f * (fr0 * fyv + fr1 * fxv);
        float sn, cs;
        __sincosf(ang, &sn, &cs);
        v[k] = cmul(v[k], make_float2(cs, sn));
    }
    fft256w<1>(v, t, ex);
    store_t(v, dst + ib, r, t, 1.0f / 256.0f);
}

// ---------- P3: rows=y: xI, modulate slice s, xF ; write T -> [kx][y] ----------
__global__ void k_p3(const float* __restrict__ object, const float* __restrict__ positions,
                     const int* __restrict__ indices, const float2* __restrict__ src,
                     float2* __restrict__ dst, int b0, int s) {
    __shared__ __align__(16) float2 lds[16 * EXREG];
    int tt = threadIdx.x;
    int t = tt & 15, g = tt >> 4;
    int rowg = blockIdx.x, m = blockIdx.y, bl = blockIdx.z;
    int y = rowg * 16 + g;
    int idx = indices[b0 + bl];
    int r0 = (int)rintf(positions[idx * 2 + 0]);
    int r1 = (int)rintf(positions[idx * 2 + 1]);
    float2* ex = lds + g * EXREG;
    size_t ib = (size_t)(bl * NM + m) * 65536;
    float2 v[16];
    load_row(v, src + ib, y, t);
    fft256w<1>(v, t, ex);
    const float2* obj = (const float2*)object + (size_t)s * HOBJ * HOBJ + (size_t)(r0 + y) * HOBJ + r1 + t;
#pragma unroll
    for (int j = 0; j < 16; ++j) {
        float2 pz = obj[16 * j];
        float2 ps = make_float2(v[j].x * (1.0f / 256.0f), v[j].y * (1.0f / 256.0f));
        v[j] = cmul(ps, pz);
    }
    fft256w<-1>(v, t, ex);
    store_t(v, dst + ib, y, t, 1.0f);
}

// ---------- P4: rows=kx: yF, *TF, yI ; write T -> [y][kx] ----------
__global__ void k_p4(const float2* __restrict__ tf_t, const float2* __restrict__ src,
                     float2* __restrict__ dst) {
    __shared__ __align__(16) float2 lds[16 * EXREG];
    int tt = threadIdx.x;
    int t = tt & 15, g = tt >> 4;
    int rowg = blockIdx.x, m = blockIdx.y, bl = blockIdx.z;
    int r = rowg * 16 + g;  // = kx
    float2* ex = lds + g * EXREG;
    size_t ib = (size_t)(bl * NM + m) * 65536;
    float2 v[16];
    load_row(v, src + ib, r, t);
    fft256w<-1>(v, t, ex);
    const float2* tr = tf_t + (size_t)r * 256 + t;
#pragma unroll
    for (int k = 0; k < 16; ++k) v[k] = cmul(v[k], tr[16 * k]);
    fft256w<1>(v, t, ex);
    store_t(v, dst + ib, r, t, 1.0f / 256.0f);
}

// ---------- P10: rows=kx: yF, |.|^2, sum modes, shifted scatter ----------
__global__ void k_p10(const float2* __restrict__ src, float* __restrict__ out, int b0) {
    __shared__ __align__(16) float2 lds[16 * EXREG];
    int tt = threadIdx.x;
    int t = tt & 15, g = tt >> 4;
    int rowg = blockIdx.x, bl = blockIdx.z;
    int r = rowg * 16 + g;  // = kx
    float2* ex = lds + g * EXREG;
    float acc[16];
#pragma unroll
    for (int k = 0; k < 16; ++k) acc[k] = 0.f;
    for (int m = 0; m < NM; ++m) {
        size_t ib = (size_t)(bl * NM + m) * 65536;
        float2 v[16];
        load_row(v, src + ib, r, t);
        fft256w<-1>(v, t, ex);
#pragma unroll
        for (int k = 0; k < 16; ++k)
            acc[k] = fmaf(v[k].x, v[k].x, fmaf(v[k].y, v[k].y, acc[k]));
    }
    float* ob = out + (size_t)(b0 + bl) * 65536;
    int xs = (r + 128) & 255;
#pragma unroll
    for (int k = 0; k < 16; ++k) {
        int ys = ((16 * k + t) + 128) & 255;
        ob[ys * 256 + xs] = acc[k] * (1.0f / 65536.0f);  // ortho norm squared
    }
}

// ---------- TF table, TRANSPOSED: tf_t[kx*256+ky] (double: phase ~1e5 rad) ----------
__global__ void k_tf_t(float2* __restrict__ tf) {
    int i = blockIdx.x * 256 + threadIdx.x;
    int kx = i >> 8, ky = i & 255;
    double fy = (double)((ky < 128) ? ky : ky - 256) / (256.0 * 1.0e-8);
    double fx = (double)((kx < 128) ? kx : kx - 256) / (256.0 * 1.0e-8);
    double ly = 1.24e-10 * fy, lx = 1.24e-10 * fx;
    double arg = 1.0 - lx * lx - ly * ly;
    float2 r = make_float2(0.f, 0.f);
    if (arg > 0.0) {
        double kz = (2.0 * M_PI / 1.24e-10) * sqrt(arg);
        double ph = 2.0e-6 * kz;
        r = make_float2((float)cos(ph), (float)sin(ph));
    }
    tf[i] = r;
}

extern "C" void kernel_launch(void* const* d_in, const int* in_sizes, int n_in,
                              void* d_out, int out_size, void* d_ws, size_t ws_size,
                              hipStream_t stream) {
    const float* object = (const float*)d_in[0];
    const float* probe = (const float*)d_in[1];
    const float* opr_w = (const float*)d_in[2];
    const float* positions = (const float*)d_in[3];
    const int* indices = (const int*)d_in[4];
    float* out = (float*)d_out;

    float2* tf = (float2*)d_ws;  // 512 KB
    size_t avail = (ws_size > (1 << 20)) ? ws_size - (1 << 20) : 0;
    long long perb = 2LL * NM * 65536 * sizeof(float2);  // 8 MB per batch entry (A+B)
    int Bc = (int)(avail / perb);
    if (Bc > NB) Bc = NB;
    if (Bc < 1) Bc = 1;
    float2* bufA = (float2*)((char*)d_ws + (1 << 20));
    float2* bufB = bufA + (size_t)Bc * NM * 65536;

    k_tf_t<<<256, 256, 0, stream>>>(tf);

    for (int b0 = 0; b0 < NB; b0 += Bc) {
        int bc = (NB - b0 < Bc) ? (NB - b0) : Bc;
        dim3 grid(16, NM, bc);
        k_p1<<<grid, 256, 0, stream>>>(probe, opr_w, indices, bufB, b0);              // -> B [kx][y]
        k_p2<<<grid, 256, 0, stream>>>(positions, indices, bufB, bufA, b0);           // -> A [y][kx]
        for (int s = 0; s < 4; ++s) {
            k_p3<<<grid, 256, 0, stream>>>(object, positions, indices, bufA, bufB, b0, s);  // -> B [kx][y]
            if (s < 3) k_p4<<<grid, 256, 0, stream>>>(tf, bufB, bufA);                      // -> A [y][kx]
        }
        dim3 gridE(16, 1, bc);
        k_p10<<<gridE, 256, 0, stream>>>(bufB, out, b0);
    }
}